// Round 17
// baseline (335.629 us; speedup 1.0000x reference)
//
#include <hip/hip_runtime.h>

#define N_ENT   100000
#define N_USR   4096
#define N_ITEM  8192
#define N_REL   32
#define N_CLS   3
#define DD      128
#define N_EDGES 800000
#define NNZ     204800

#define CAP_E   64
#define CAP_U   128

typedef __attribute__((ext_vector_type(8))) short short8;
typedef __attribute__((ext_vector_type(4))) short short4v;
typedef __attribute__((ext_vector_type(4))) float f32x4;

static __device__ __forceinline__ unsigned short f2bf(float x) {
    unsigned int u = __builtin_bit_cast(unsigned int, x);
    u = (u + 0x7fffu + ((u >> 16) & 1u)) >> 16;
    return (unsigned short)u;
}
static __device__ __forceinline__ float bflo(unsigned int v) {
    return __uint_as_float(v << 16);
}
static __device__ __forceinline__ float bfhi(unsigned int v) {
    return __uint_as_float(v & 0xffff0000u);
}

// ---------------- node 1: full prep {ent_att | item2 | zero | uatt} --------
// All branches are read-streaming / trivial (no random writes) — compatible.
// ent_att first (longest blocks dispatch first).
#define EAB ((N_ENT + 255) / 256)           // 391
#define ZB  ((N_ENT + N_USR + 255) / 256)   // 407

__global__ __launch_bounds__(256) void k_prep_full(const float* __restrict__ ent,
                                                   const float* __restrict__ rel,
                                                   float* __restrict__ att,
                                                   unsigned short* __restrict__ entbf,
                                                   unsigned short* __restrict__ relbf,
                                                   int* __restrict__ cnt,
                                                   const float* __restrict__ item,
                                                   unsigned short* __restrict__ Bt,
                                                   const float* __restrict__ usr,
                                                   const float* __restrict__ w,
                                                   float* __restrict__ uatt) {
    __shared__ float smem[N_REL * DD];      // 16 KB union
    int bx = blockIdx.x;

    if (bx < EAB) {                         // ---- ent_att + bf16 tables ----
        for (int i = threadIdx.x; i < N_REL * DD; i += 256) smem[i] = rel[i];
        __syncthreads();
        if (bx == 0) {
            for (int i = threadIdx.x; i < N_REL * DD; i += 256)
                relbf[i] = f2bf(smem[i]);
        }
        int e = bx * 256 + threadIdx.x;
        if (e >= N_ENT) return;
        const float4* row = (const float4*)(ent + (size_t)e * DD);
        unsigned short* brow = entbf + (size_t)e * DD;
        float acc[N_REL];
#pragma unroll
        for (int r = 0; r < N_REL; ++r) acc[r] = 0.f;
        for (int dq = 0; dq < DD / 4; ++dq) {
            float4 v = row[dq];
            ushort4 bv;
            bv.x = f2bf(v.x); bv.y = f2bf(v.y); bv.z = f2bf(v.z); bv.w = f2bf(v.w);
            *(ushort4*)(brow + dq * 4) = bv;
#pragma unroll
            for (int r = 0; r < N_REL; ++r) {
                float4 ww = *(const float4*)&smem[r * DD + dq * 4];
                acc[r] += v.x * ww.x + v.y * ww.y + v.z * ww.z + v.w * ww.w;
            }
        }
        float m = acc[0];
#pragma unroll
        for (int r = 1; r < N_REL; ++r) m = fmaxf(m, acc[r]);
        float s = 0.f;
#pragma unroll
        for (int r = 0; r < N_REL; ++r) { acc[r] = __expf(acc[r] - m); s += acc[r]; }
        float inv = 1.f / s;
        float* o = att + (size_t)e * N_REL;
#pragma unroll
        for (int r = 0; r < N_REL; ++r) o[r] = acc[r] * inv;
        return;
    }
    bx -= EAB;

    if (bx < 1024) {                        // ---- item2 tiled transpose -> Bt ----
        float (*tile)[33] = (float(*)[33])smem;
        float* ssum = smem + 32 * 33;
        const int b2 = bx & 255, by = bx >> 8;
        const int tx = threadIdx.x & 31, ty = threadIdx.x >> 5;
        const int i0 = b2 * 32, d0 = by * 32;
        if (threadIdx.x < 32) {
            float s = 0.f;
            for (int r = 0; r < N_REL; ++r) s += rel[r * DD + d0 + threadIdx.x];
            ssum[threadIdx.x] = s;
        }
#pragma unroll
        for (int rr = 0; rr < 4; ++rr)
            tile[ty + 8 * rr][tx] = item[(size_t)(i0 + ty + 8 * rr) * DD + d0 + tx];
        __syncthreads();
#pragma unroll
        for (int rr = 0; rr < 4; ++rr) {
            int d = d0 + ty + 8 * rr;
            Bt[(size_t)d * N_ITEM + i0 + tx] = f2bf(tile[tx][ty + 8 * rr] * ssum[ty + 8 * rr]);
        }
        return;
    }
    bx -= 1024;

    if (bx < ZB) {                          // ---- zero cnt ----
        int i = bx * 256 + threadIdx.x;
        if (i < N_ENT + N_USR) cnt[i] = 0;
        return;
    }
    bx -= ZB;

    {                                       // ---- user_cls_att (16 blocks) ----
        for (int i = threadIdx.x; i < N_CLS * DD; i += 256) smem[i] = w[i];
        __syncthreads();
        int u = bx * 256 + threadIdx.x;
        const float4* row = (const float4*)(usr + (size_t)u * DD);
        float acc[3] = {0.f, 0.f, 0.f};
        for (int dq = 0; dq < DD / 4; ++dq) {
            float4 v = row[dq];
#pragma unroll
            for (int c = 0; c < 3; ++c) {
                float4 ww = *(const float4*)&smem[c * DD + dq * 4];
                acc[c] += v.x * ww.x + v.y * ww.y + v.z * ww.z + v.w * ww.w;
            }
        }
        float m = fmaxf(acc[0], fmaxf(acc[1], acc[2]));
        float s = 0.f;
#pragma unroll
        for (int c = 0; c < 3; ++c) { acc[c] = __expf(acc[c] - m); s += acc[c]; }
        float inv = 1.f / s;
#pragma unroll
        for (int c = 0; c < 3; ++c) uatt[u * 3 + c] = acc[c] * inv;
    }
}

// ---------------- node 2: combine (dedicated streaming) --------------------
// A[u,i] = bf16(sum_c uatt[u,c]*icm[c,u,i]); grid-stride, 2048 blocks
// (m13 float4-copy pattern). 402MB read + 67MB write, target >=4.5 TB/s.
#define PLANE  ((long long)N_USR * N_ITEM)    // 33,554,432
#define PLANE4 (PLANE / 4)                    // 8,388,608 float4

__global__ __launch_bounds__(256) void k_combine(const float* __restrict__ icm,
                                                 const float* __restrict__ uatt,
                                                 unsigned short* __restrict__ Abf) {
    const float4* icm4 = (const float4*)icm;
    ushort4* out4 = (ushort4*)Abf;
    long long idx = (long long)blockIdx.x * 256 + threadIdx.x;
    const long long stride = (long long)gridDim.x * 256;
    for (; idx < PLANE4; idx += stride) {
        const int u = (int)(idx >> 11);       // 2048 float4 per user row
        const float a0 = uatt[u * 3 + 0];
        const float a1 = uatt[u * 3 + 1];
        const float a2 = uatt[u * 3 + 2];
        float4 f0 = icm4[idx];
        float4 f1 = icm4[idx + PLANE4];
        float4 f2 = icm4[idx + 2 * PLANE4];
        ushort4 o;
        o.x = f2bf(a0 * f0.x + a1 * f1.x + a2 * f2.x);
        o.y = f2bf(a0 * f0.y + a1 * f1.y + a2 * f2.y);
        o.z = f2bf(a0 * f0.z + a1 * f1.z + a2 * f2.z);
        o.w = f2bf(a0 * f0.w + a1 * f1.w + a2 * f2.w);
        out4[idx] = o;
    }
}

// ---------------- node 3: bucket scatter (dedicated) -----------------------
#define SCAT_BLOCKS ((N_EDGES + 255) / 256)   // 3125

__global__ __launch_bounds__(256) void k_scatter(const int* __restrict__ eidx,
                                                 const int* __restrict__ etyp,
                                                 const float* __restrict__ eimp,
                                                 const int* __restrict__ irow,
                                                 const int* __restrict__ icol,
                                                 const float* __restrict__ ival,
                                                 int* __restrict__ cnt,
                                                 int2* __restrict__ pack_e,
                                                 int2* __restrict__ pack_u) {
    int i = blockIdx.x * 256 + threadIdx.x;
    if (i < N_EDGES) {
        int h = eidx[i], tl = eidx[N_EDGES + i], r = etyp[i];
        int p = atomicAdd(&cnt[h], 1);
        if (p < CAP_E) {
            int2 pk;
            pk.x = tl | (r << 24);
            pk.y = __float_as_int(eimp[i]);
            pack_e[(size_t)h * CAP_E + p] = pk;
        }
    }
    if (i < NNZ) {
        int u = irow[i];
        int p = atomicAdd(&cnt[N_ENT + u], 1);
        if (p < CAP_U) {
            int2 pk;
            pk.x = icol[i];
            pk.y = __float_as_int(ival[i]);
            pack_u[(size_t)u * CAP_U + p] = pk;
        }
    }
}

// ---------------- node 4: GEMM on pre-combined bf16 A (L3-resident) --------
#define BM 64
#define BK 32
#define SPLITK 16
#define KCH (N_ITEM / SPLITK)                 // 512
#define NSTEP (KCH / BK)                      // 16

__global__ __launch_bounds__(256) void k_gemm2(const unsigned short* __restrict__ Abf,
                                               const unsigned short* __restrict__ Bt,
                                               float* __restrict__ part) {
    __shared__ unsigned short sA[BM][40];
    __shared__ unsigned short sB[DD][40];

    const int t  = threadIdx.x;
    const int m0 = blockIdx.x * BM;
    const long long k0b = (long long)blockIdx.y * KCH;

    const int ua = t >> 3;
    const int qa = t & 7;
    const int db = t >> 2;
    const int qb = t & 3;

    const int lane = t & 63;
    const int wv = t >> 6;
    const int wm = wv >> 1, wn = wv & 1;
    const int la = lane & 15, lb = lane >> 4;

    f32x4 acc[2][4];
#pragma unroll
    for (int mi = 0; mi < 2; ++mi)
#pragma unroll
        for (int ni = 0; ni < 4; ++ni) {
            f32x4 z = {0.f, 0.f, 0.f, 0.f};
            acc[mi][ni] = z;
        }

    short4v rA0, rA1;
    short8 rB0, rB1;

#define GISSUE(step) do {                                                     \
    const long long k0_ = k0b + (long long)(step) * BK;                       \
    rA0 = *(const short4v*)(Abf + (size_t)(m0 + ua) * N_ITEM + k0_ + qa * 4); \
    rA1 = *(const short4v*)(Abf + (size_t)(m0 + ua + 32) * N_ITEM + k0_ + qa * 4); \
    rB0 = *(const short8*)(Bt + (size_t)db * N_ITEM + k0_ + qb * 8);          \
    rB1 = *(const short8*)(Bt + (size_t)(db + 64) * N_ITEM + k0_ + qb * 8);   \
} while (0)

    GISSUE(0);

#pragma unroll 1
    for (int s = 0; s < NSTEP; ++s) {
        __syncthreads();
        *(short4v*)(&sA[ua][qa * 4]) = rA0;
        *(short4v*)(&sA[ua + 32][qa * 4]) = rA1;
        *(short8*)(&sB[db][qb * 8]) = rB0;
        *(short8*)(&sB[db + 64][qb * 8]) = rB1;
        __syncthreads();
        if (s + 1 < NSTEP) GISSUE(s + 1);

        short8 af[2], bfr[4];
#pragma unroll
        for (int mi = 0; mi < 2; ++mi)
            af[mi] = *(const short8*)(&sA[wm * 32 + mi * 16 + la][0] + lb * 8);
#pragma unroll
        for (int ni = 0; ni < 4; ++ni)
            bfr[ni] = *(const short8*)(&sB[wn * 64 + ni * 16 + la][0] + lb * 8);
#pragma unroll
        for (int mi = 0; mi < 2; ++mi)
#pragma unroll
            for (int ni = 0; ni < 4; ++ni)
                acc[mi][ni] = __builtin_amdgcn_mfma_f32_16x16x32_bf16(
                    af[mi], bfr[ni], acc[mi][ni], 0, 0, 0);
    }
#undef GISSUE

    float* pbase = part + (size_t)blockIdx.y * ((size_t)N_USR * DD);
#pragma unroll
    for (int mi = 0; mi < 2; ++mi)
#pragma unroll
        for (int ni = 0; ni < 4; ++ni)
#pragma unroll
            for (int r = 0; r < 4; ++r) {
                int row = m0 + wm * 32 + mi * 16 + lb * 4 + r;
                int col = wn * 64 + ni * 16 + la;
                pbase[(size_t)row * DD + col] = acc[mi][ni][r];
            }
}

// ---------------- node 5: {edge agg (16-lane groups) || user gather} -------
#define EDGE_BLOCKS (N_ENT / 16)     // 6250
#define USER_BLOCKS (N_USR / 4)      // 1024

__global__ __launch_bounds__(256) void k_node3(const unsigned short* __restrict__ entbf,
                                               const unsigned short* __restrict__ relbf,
                                               const float* __restrict__ att,
                                               const int2* __restrict__ pack_e,
                                               const int2* __restrict__ pack_u,
                                               const int* __restrict__ cnt,
                                               const float* __restrict__ part,
                                               float* __restrict__ out_ent,
                                               float* __restrict__ out_usr) {
    const int lane = threadIdx.x & 63;

    if (blockIdx.x < EDGE_BLOCKS) {
        const int wid = blockIdx.x * 4 + (threadIdx.x >> 6);
        const int l15 = lane & 15;
        const int grp = lane >> 4;
#pragma unroll 1
        for (int hh = 0; hh < 4; ++hh) {
            const int h = wid * 4 + hh;
            const int n = min(cnt[h], CAP_E);
            const float attv = att[(size_t)h * N_REL + (lane & 31)];
            const int2* seg = pack_e + (size_t)h * CAP_E;
            float acc[8];
#pragma unroll
            for (int e = 0; e < 8; ++e) acc[e] = 0.f;
            for (int j = 0; j < n; j += 8) {
                const int e0 = j + grp, e1 = j + 4 + grp;
                int2 p0 = seg[min(e0, n - 1)];
                int2 p1 = seg[min(e1, n - 1)];
                const int r0 = ((unsigned)p0.x) >> 24;
                const int r1 = ((unsigned)p1.x) >> 24;
                float s0 = __shfl(attv, r0, 64) * __int_as_float(p0.y);
                float s1 = __shfl(attv, r1, 64) * __int_as_float(p1.y);
                s0 = (e0 < n) ? s0 : 0.f;
                s1 = (e1 < n) ? s1 : 0.f;
                uint4 b0 = ((const uint4*)(entbf + (size_t)(p0.x & 0xFFFFFF) * DD))[l15];
                uint4 b1 = ((const uint4*)(entbf + (size_t)(p1.x & 0xFFFFFF) * DD))[l15];
                uint4 v0 = ((const uint4*)(relbf + (size_t)r0 * DD))[l15];
                uint4 v1 = ((const uint4*)(relbf + (size_t)r1 * DD))[l15];
                const unsigned* bp0 = (const unsigned*)&b0;
                const unsigned* bp1 = (const unsigned*)&b1;
                const unsigned* vp0 = (const unsigned*)&v0;
                const unsigned* vp1 = (const unsigned*)&v1;
#pragma unroll
                for (int q = 0; q < 4; ++q) {
                    acc[2 * q]     = fmaf(bflo(bp0[q]) * bflo(vp0[q]), s0, acc[2 * q]);
                    acc[2 * q + 1] = fmaf(bfhi(bp0[q]) * bfhi(vp0[q]), s0, acc[2 * q + 1]);
                    acc[2 * q]     = fmaf(bflo(bp1[q]) * bflo(vp1[q]), s1, acc[2 * q]);
                    acc[2 * q + 1] = fmaf(bfhi(bp1[q]) * bfhi(vp1[q]), s1, acc[2 * q + 1]);
                }
            }
#pragma unroll
            for (int e = 0; e < 8; ++e) {
                acc[e] += __shfl_xor(acc[e], 16, 64);
                acc[e] += __shfl_xor(acc[e], 32, 64);
            }
            if (lane < 16) {
                float4 o0 = {acc[0], acc[1], acc[2], acc[3]};
                float4 o1 = {acc[4], acc[5], acc[6], acc[7]};
                float4* dst = (float4*)(out_ent + (size_t)h * DD) + l15 * 2;
                dst[0] = o0;
                dst[1] = o1;
            }
        }
    } else {
        const int u = (blockIdx.x - EDGE_BLOCKS) * 4 + (threadIdx.x >> 6);
        const int n = min(cnt[N_ENT + u], CAP_U);
        const int2* seg = pack_u + (size_t)u * CAP_U;
        float ax = 0.f, ay = 0.f;
        for (int j = 0; j < n; j += 8) {
            int2 pk[8];
#pragma unroll
            for (int k = 0; k < 8; ++k) pk[k] = seg[min(j + k, n - 1)];
            unsigned int bv[8];
            float sc[8];
#pragma unroll
            for (int k = 0; k < 8; ++k) {
                sc[k] = (j + k < n) ? __int_as_float(pk[k].y) : 0.f;
                bv[k] = ((const unsigned int*)(entbf + (size_t)pk[k].x * DD))[lane];
            }
#pragma unroll
            for (int k = 0; k < 8; ++k) {
                ax = fmaf(bflo(bv[k]), sc[k], ax);
                ay = fmaf(bfhi(bv[k]), sc[k], ay);
            }
        }
#pragma unroll
        for (int k = 0; k < SPLITK; ++k) {
            float2 p = ((const float2*)(part + (size_t)k * N_USR * DD + (size_t)u * DD))[lane];
            ax += p.x;
            ay += p.y;
        }
        float2 o; o.x = ax; o.y = ay;
        ((float2*)(out_usr + (size_t)u * DD))[lane] = o;
    }
}

// ---------------------------------------------------------------------------
static constexpr size_t algn(size_t x) { return (x + 255) & ~(size_t)255; }

extern "C" void kernel_launch(void* const* d_in, const int* in_sizes, int n_in,
                              void* d_out, int out_size, void* d_ws, size_t ws_size,
                              hipStream_t stream) {
    const float* ent  = (const float*)d_in[0];
    const float* item = (const float*)d_in[1];
    const float* usr  = (const float*)d_in[2];
    const float* rel  = (const float*)d_in[4];
    const int*   eidx = (const int*)d_in[5];
    const int*   etyp = (const int*)d_in[6];
    const float* eimp = (const float*)d_in[7];
    const int*   irow = (const int*)d_in[8];
    const int*   icol = (const int*)d_in[9];
    const float* ival = (const float*)d_in[10];
    const float* uclw = (const float*)d_in[13];
    const float* icm  = (const float*)d_in[14];

    float* out_ent = (float*)d_out;
    float* out_usr = out_ent + (size_t)N_ENT * DD;

    char* w = (char*)d_ws;
    size_t o = 0;
    float* ws_att  = (float*)(w + o);  o = algn(o + (size_t)N_ENT * N_REL * 4);
    float* ws_uatt = (float*)(w + o);  o = algn(o + (size_t)N_USR * N_CLS * 4);
    unsigned short* ws_Bt    = (unsigned short*)(w + o); o = algn(o + (size_t)DD * N_ITEM * 2);
    unsigned short* ws_entbf = (unsigned short*)(w + o); o = algn(o + (size_t)N_ENT * DD * 2);
    unsigned short* ws_relbf = (unsigned short*)(w + o); o = algn(o + (size_t)N_REL * DD * 2);
    unsigned short* ws_Abf   = (unsigned short*)(w + o); o = algn(o + (size_t)N_USR * N_ITEM * 2);
    int*  ws_cnt   = (int*)(w + o);  o = algn(o + (size_t)(N_ENT + N_USR) * 4);
    int2* pack_e   = (int2*)(w + o); o = algn(o + (size_t)N_ENT * CAP_E * 8);
    int2* pack_u   = (int2*)(w + o); o = algn(o + (size_t)N_USR * CAP_U * 8);
    float* part    = (float*)(w + o); o = algn(o + (size_t)SPLITK * N_USR * DD * 4);

    (void)in_sizes; (void)n_in; (void)ws_size; (void)out_size;

    // 5 nodes, de-interfered:
    // prep_full -> combine -> scatter -> gemm2 -> {edge || user}
    k_prep_full<<<EAB + 1024 + ZB + 16, 256, 0, stream>>>(ent, rel, ws_att, ws_entbf,
                                                          ws_relbf, ws_cnt, item, ws_Bt,
                                                          usr, uclw, ws_uatt);
    k_combine<<<2048, 256, 0, stream>>>(icm, ws_uatt, ws_Abf);
    k_scatter<<<SCAT_BLOCKS, 256, 0, stream>>>(eidx, etyp, eimp, irow, icol, ival,
                                               ws_cnt, pack_e, pack_u);
    k_gemm2<<<dim3(N_USR / BM, SPLITK), 256, 0, stream>>>(ws_Abf, ws_Bt, part);
    k_node3<<<EDGE_BLOCKS + USER_BLOCKS, 256, 0, stream>>>(ws_entbf, ws_relbf, ws_att,
                                                           pack_e, pack_u, ws_cnt, part,
                                                           out_ent, out_usr);
}

// Round 18
// 300.425 us; speedup vs baseline: 1.1172x; 1.1172x over previous
//
#include <hip/hip_runtime.h>

#define N_ENT   100000
#define N_USR   4096
#define N_ITEM  8192
#define N_REL   32
#define N_CLS   3
#define DD      128
#define N_EDGES 800000
#define NNZ     204800

#define CAP_E   64
#define CAP_U   128

typedef __attribute__((ext_vector_type(8))) short short8;
typedef __attribute__((ext_vector_type(4))) short short4v;
typedef __attribute__((ext_vector_type(4))) float f32x4;

static __device__ __forceinline__ unsigned short f2bf(float x) {
    unsigned int u = __builtin_bit_cast(unsigned int, x);
    u = (u + 0x7fffu + ((u >> 16) & 1u)) >> 16;
    return (unsigned short)u;
}
static __device__ __forceinline__ float bflo(unsigned int v) {
    return __uint_as_float(v << 16);
}
static __device__ __forceinline__ float bfhi(unsigned int v) {
    return __uint_as_float(v & 0xffff0000u);
}

// ---------------- node 1: light prep {zero cnt | item2 -> Bt | uatt} -------
#define ZB  ((N_ENT + N_USR + 255) / 256)   // 407

__global__ __launch_bounds__(256) void k_prep_light(const float* __restrict__ rel,
                                                    int* __restrict__ cnt,
                                                    const float* __restrict__ item,
                                                    unsigned short* __restrict__ Bt,
                                                    const float* __restrict__ usr,
                                                    const float* __restrict__ w,
                                                    float* __restrict__ uatt) {
    __shared__ float smem[32 * 33 + 32];
    int bx = blockIdx.x;

    if (bx < ZB) {
        int i = bx * 256 + threadIdx.x;
        if (i < N_ENT + N_USR) cnt[i] = 0;
        return;
    }
    bx -= ZB;

    if (bx < 1024) {                        // ---- item2 tiled transpose -> Bt ----
        float (*tile)[33] = (float(*)[33])smem;
        float* ssum = smem + 32 * 33;
        const int b2 = bx & 255, by = bx >> 8;
        const int tx = threadIdx.x & 31, ty = threadIdx.x >> 5;
        const int i0 = b2 * 32, d0 = by * 32;
        if (threadIdx.x < 32) {
            float s = 0.f;
            for (int r = 0; r < N_REL; ++r) s += rel[r * DD + d0 + threadIdx.x];
            ssum[threadIdx.x] = s;
        }
#pragma unroll
        for (int rr = 0; rr < 4; ++rr)
            tile[ty + 8 * rr][tx] = item[(size_t)(i0 + ty + 8 * rr) * DD + d0 + tx];
        __syncthreads();
#pragma unroll
        for (int rr = 0; rr < 4; ++rr) {
            int d = d0 + ty + 8 * rr;
            Bt[(size_t)d * N_ITEM + i0 + tx] = f2bf(tile[tx][ty + 8 * rr] * ssum[ty + 8 * rr]);
        }
        return;
    }
    bx -= 1024;

    {                                       // ---- user_cls_att (16 blocks) ----
        for (int i = threadIdx.x; i < N_CLS * DD; i += 256) smem[i] = w[i];
        __syncthreads();
        int u = bx * 256 + threadIdx.x;
        const float4* row = (const float4*)(usr + (size_t)u * DD);
        float acc[3] = {0.f, 0.f, 0.f};
        for (int dq = 0; dq < DD / 4; ++dq) {
            float4 v = row[dq];
#pragma unroll
            for (int c = 0; c < 3; ++c) {
                float4 ww = *(const float4*)&smem[c * DD + dq * 4];
                acc[c] += v.x * ww.x + v.y * ww.y + v.z * ww.z + v.w * ww.w;
            }
        }
        float m = fmaxf(acc[0], fmaxf(acc[1], acc[2]));
        float s = 0.f;
#pragma unroll
        for (int c = 0; c < 3; ++c) { acc[c] = __expf(acc[c] - m); s += acc[c]; }
        float inv = 1.f / s;
#pragma unroll
        for (int c = 0; c < 3; ++c) uatt[u * 3 + c] = acc[c] * inv;
    }
}

// ---------------- node 2: {combine(rotated) || ent_att || scatter} ---------
// r17 finding: three different kernels (direct gemm, merged combine, serial
// combine) all cap at ~2.2-2.3 TB/s; common factor = reading 3 icm planes at
// 2^27-byte offsets simultaneously -> DRAM channel hot-spotting. Fix: phase-
// rotated accumulation — each block reads ONE plane at a time, plane order
// rotated by bid%3 so blocks spread across planes; register accumulator.
#define PLANE  ((long long)N_USR * N_ITEM)    // 33,554,432
#define PLANE4 (PLANE / 4)                    // 8,388,608 float4
#define CB_BLOCKS ((int)(PLANE / 4096))       // 8192 (4096 elems per block)
#define EAB ((N_ENT + 255) / 256)             // 391
#define SCAT_BLOCKS ((N_EDGES + 255) / 256)   // 3125

__global__ __launch_bounds__(256) void k_node2(const float* __restrict__ icm,
                                               const float* __restrict__ uatt,
                                               unsigned short* __restrict__ Abf,
                                               const float* __restrict__ ent,
                                               const float* __restrict__ rel,
                                               float* __restrict__ att,
                                               unsigned short* __restrict__ entbf,
                                               unsigned short* __restrict__ relbf,
                                               const int* __restrict__ eidx,
                                               const int* __restrict__ etyp,
                                               const float* __restrict__ eimp,
                                               const int* __restrict__ irow,
                                               const int* __restrict__ icol,
                                               const float* __restrict__ ival,
                                               int* __restrict__ cnt,
                                               int2* __restrict__ pack_e,
                                               int2* __restrict__ pack_u) {
    __shared__ float smemf[N_REL * DD];       // ent_att branch only

    if (blockIdx.x < CB_BLOCKS) {
        // ================= combine, phase-rotated ==========================
        const int bid = blockIdx.x;           // 2 blocks per user (4096 elems)
        const int u = bid >> 1;
        const float a0 = uatt[u * 3 + 0];
        const float a1 = uatt[u * 3 + 1];
        const float a2 = uatt[u * 3 + 2];
        const float4* icm4 = (const float4*)icm;
        const long long base4 = (long long)bid * 1024 + threadIdx.x;
        float racc[16];
#pragma unroll
        for (int j = 0; j < 16; ++j) racc[j] = 0.f;
#pragma unroll
        for (int p = 0; p < 3; ++p) {
            const int c = (bid + p) % 3;      // rotate plane order per block
            const float ac = (c == 0) ? a0 : ((c == 1) ? a1 : a2);
            const float4* src = icm4 + (long long)c * PLANE4 + base4;
            float4 f[4];
#pragma unroll
            for (int j = 0; j < 4; ++j) f[j] = src[j * 256];
#pragma unroll
            for (int j = 0; j < 4; ++j) {
                racc[4 * j + 0] = fmaf(ac, f[j].x, racc[4 * j + 0]);
                racc[4 * j + 1] = fmaf(ac, f[j].y, racc[4 * j + 1]);
                racc[4 * j + 2] = fmaf(ac, f[j].z, racc[4 * j + 2]);
                racc[4 * j + 3] = fmaf(ac, f[j].w, racc[4 * j + 3]);
            }
        }
        ushort4* out4 = (ushort4*)Abf;
#pragma unroll
        for (int j = 0; j < 4; ++j) {
            ushort4 o;
            o.x = f2bf(racc[4 * j + 0]);
            o.y = f2bf(racc[4 * j + 1]);
            o.z = f2bf(racc[4 * j + 2]);
            o.w = f2bf(racc[4 * j + 3]);
            out4[base4 + j * 256] = o;
        }
        return;
    }

    if (blockIdx.x < CB_BLOCKS + EAB) {
        // ================= ent_att + bf16 tables ===========================
        int bx = blockIdx.x - CB_BLOCKS;
        for (int i = threadIdx.x; i < N_REL * DD; i += 256) smemf[i] = rel[i];
        __syncthreads();
        if (bx == 0) {
            for (int i = threadIdx.x; i < N_REL * DD; i += 256)
                relbf[i] = f2bf(smemf[i]);
        }
        int e = bx * 256 + threadIdx.x;
        if (e >= N_ENT) return;
        const float4* row = (const float4*)(ent + (size_t)e * DD);
        unsigned short* brow = entbf + (size_t)e * DD;
        float acc[N_REL];
#pragma unroll
        for (int r = 0; r < N_REL; ++r) acc[r] = 0.f;
        for (int dq = 0; dq < DD / 4; ++dq) {
            float4 v = row[dq];
            ushort4 bv;
            bv.x = f2bf(v.x); bv.y = f2bf(v.y); bv.z = f2bf(v.z); bv.w = f2bf(v.w);
            *(ushort4*)(brow + dq * 4) = bv;
#pragma unroll
            for (int r = 0; r < N_REL; ++r) {
                float4 ww = *(const float4*)&smemf[r * DD + dq * 4];
                acc[r] += v.x * ww.x + v.y * ww.y + v.z * ww.z + v.w * ww.w;
            }
        }
        float m = acc[0];
#pragma unroll
        for (int r = 1; r < N_REL; ++r) m = fmaxf(m, acc[r]);
        float s = 0.f;
#pragma unroll
        for (int r = 0; r < N_REL; ++r) { acc[r] = __expf(acc[r] - m); s += acc[r]; }
        float inv = 1.f / s;
        float* o = att + (size_t)e * N_REL;
#pragma unroll
        for (int r = 0; r < N_REL; ++r) o[r] = acc[r] * inv;
        return;
    }

    {
        // ================= bucket scatter ==================================
        int i = (blockIdx.x - CB_BLOCKS - EAB) * 256 + threadIdx.x;
        if (i < N_EDGES) {
            int h = eidx[i], tl = eidx[N_EDGES + i], r = etyp[i];
            int p = atomicAdd(&cnt[h], 1);
            if (p < CAP_E) {
                int2 pk;
                pk.x = tl | (r << 24);
                pk.y = __float_as_int(eimp[i]);
                pack_e[(size_t)h * CAP_E + p] = pk;
            }
        }
        if (i < NNZ) {
            int u = irow[i];
            int p = atomicAdd(&cnt[N_ENT + u], 1);
            if (p < CAP_U) {
                int2 pk;
                pk.x = icol[i];
                pk.y = __float_as_int(ival[i]);
                pack_u[(size_t)u * CAP_U + p] = pk;
            }
        }
    }
}

// ---------------- node 3: GEMM on pre-combined bf16 A (L3-resident) --------
#define BM 64
#define BK 32
#define SPLITK 16
#define KCH (N_ITEM / SPLITK)                 // 512
#define NSTEP (KCH / BK)                      // 16

__global__ __launch_bounds__(256) void k_gemm2(const unsigned short* __restrict__ Abf,
                                               const unsigned short* __restrict__ Bt,
                                               float* __restrict__ part) {
    __shared__ unsigned short sA[BM][40];
    __shared__ unsigned short sB[DD][40];

    const int t  = threadIdx.x;
    const int m0 = blockIdx.x * BM;
    const long long k0b = (long long)blockIdx.y * KCH;

    const int ua = t >> 3;
    const int qa = t & 7;
    const int db = t >> 2;
    const int qb = t & 3;

    const int lane = t & 63;
    const int wv = t >> 6;
    const int wm = wv >> 1, wn = wv & 1;
    const int la = lane & 15, lb = lane >> 4;

    f32x4 acc[2][4];
#pragma unroll
    for (int mi = 0; mi < 2; ++mi)
#pragma unroll
        for (int ni = 0; ni < 4; ++ni) {
            f32x4 z = {0.f, 0.f, 0.f, 0.f};
            acc[mi][ni] = z;
        }

    short4v rA0, rA1;
    short8 rB0, rB1;

#define GISSUE(step) do {                                                     \
    const long long k0_ = k0b + (long long)(step) * BK;                       \
    rA0 = *(const short4v*)(Abf + (size_t)(m0 + ua) * N_ITEM + k0_ + qa * 4); \
    rA1 = *(const short4v*)(Abf + (size_t)(m0 + ua + 32) * N_ITEM + k0_ + qa * 4); \
    rB0 = *(const short8*)(Bt + (size_t)db * N_ITEM + k0_ + qb * 8);          \
    rB1 = *(const short8*)(Bt + (size_t)(db + 64) * N_ITEM + k0_ + qb * 8);   \
} while (0)

    GISSUE(0);

#pragma unroll 1
    for (int s = 0; s < NSTEP; ++s) {
        __syncthreads();
        *(short4v*)(&sA[ua][qa * 4]) = rA0;
        *(short4v*)(&sA[ua + 32][qa * 4]) = rA1;
        *(short8*)(&sB[db][qb * 8]) = rB0;
        *(short8*)(&sB[db + 64][qb * 8]) = rB1;
        __syncthreads();
        if (s + 1 < NSTEP) GISSUE(s + 1);

        short8 af[2], bfr[4];
#pragma unroll
        for (int mi = 0; mi < 2; ++mi)
            af[mi] = *(const short8*)(&sA[wm * 32 + mi * 16 + la][0] + lb * 8);
#pragma unroll
        for (int ni = 0; ni < 4; ++ni)
            bfr[ni] = *(const short8*)(&sB[wn * 64 + ni * 16 + la][0] + lb * 8);
#pragma unroll
        for (int mi = 0; mi < 2; ++mi)
#pragma unroll
            for (int ni = 0; ni < 4; ++ni)
                acc[mi][ni] = __builtin_amdgcn_mfma_f32_16x16x32_bf16(
                    af[mi], bfr[ni], acc[mi][ni], 0, 0, 0);
    }
#undef GISSUE

    float* pbase = part + (size_t)blockIdx.y * ((size_t)N_USR * DD);
#pragma unroll
    for (int mi = 0; mi < 2; ++mi)
#pragma unroll
        for (int ni = 0; ni < 4; ++ni)
#pragma unroll
            for (int r = 0; r < 4; ++r) {
                int row = m0 + wm * 32 + mi * 16 + lb * 4 + r;
                int col = wn * 64 + ni * 16 + la;
                pbase[(size_t)row * DD + col] = acc[mi][ni][r];
            }
}

// ---------------- node 4: {edge agg (16-lane groups) || user gather} -------
#define EDGE_BLOCKS (N_ENT / 16)     // 6250
#define USER_BLOCKS (N_USR / 4)      // 1024

__global__ __launch_bounds__(256) void k_node3(const unsigned short* __restrict__ entbf,
                                               const unsigned short* __restrict__ relbf,
                                               const float* __restrict__ att,
                                               const int2* __restrict__ pack_e,
                                               const int2* __restrict__ pack_u,
                                               const int* __restrict__ cnt,
                                               const float* __restrict__ part,
                                               float* __restrict__ out_ent,
                                               float* __restrict__ out_usr) {
    const int lane = threadIdx.x & 63;

    if (blockIdx.x < EDGE_BLOCKS) {
        const int wid = blockIdx.x * 4 + (threadIdx.x >> 6);
        const int l15 = lane & 15;
        const int grp = lane >> 4;
#pragma unroll 1
        for (int hh = 0; hh < 4; ++hh) {
            const int h = wid * 4 + hh;
            const int n = min(cnt[h], CAP_E);
            const float attv = att[(size_t)h * N_REL + (lane & 31)];
            const int2* seg = pack_e + (size_t)h * CAP_E;
            float acc[8];
#pragma unroll
            for (int e = 0; e < 8; ++e) acc[e] = 0.f;
            for (int j = 0; j < n; j += 8) {
                const int e0 = j + grp, e1 = j + 4 + grp;
                int2 p0 = seg[min(e0, n - 1)];
                int2 p1 = seg[min(e1, n - 1)];
                const int r0 = ((unsigned)p0.x) >> 24;
                const int r1 = ((unsigned)p1.x) >> 24;
                float s0 = __shfl(attv, r0, 64) * __int_as_float(p0.y);
                float s1 = __shfl(attv, r1, 64) * __int_as_float(p1.y);
                s0 = (e0 < n) ? s0 : 0.f;
                s1 = (e1 < n) ? s1 : 0.f;
                uint4 b0 = ((const uint4*)(entbf + (size_t)(p0.x & 0xFFFFFF) * DD))[l15];
                uint4 b1 = ((const uint4*)(entbf + (size_t)(p1.x & 0xFFFFFF) * DD))[l15];
                uint4 v0 = ((const uint4*)(relbf + (size_t)r0 * DD))[l15];
                uint4 v1 = ((const uint4*)(relbf + (size_t)r1 * DD))[l15];
                const unsigned* bp0 = (const unsigned*)&b0;
                const unsigned* bp1 = (const unsigned*)&b1;
                const unsigned* vp0 = (const unsigned*)&v0;
                const unsigned* vp1 = (const unsigned*)&v1;
#pragma unroll
                for (int q = 0; q < 4; ++q) {
                    acc[2 * q]     = fmaf(bflo(bp0[q]) * bflo(vp0[q]), s0, acc[2 * q]);
                    acc[2 * q + 1] = fmaf(bfhi(bp0[q]) * bfhi(vp0[q]), s0, acc[2 * q + 1]);
                    acc[2 * q]     = fmaf(bflo(bp1[q]) * bflo(vp1[q]), s1, acc[2 * q]);
                    acc[2 * q + 1] = fmaf(bfhi(bp1[q]) * bfhi(vp1[q]), s1, acc[2 * q + 1]);
                }
            }
#pragma unroll
            for (int e = 0; e < 8; ++e) {
                acc[e] += __shfl_xor(acc[e], 16, 64);
                acc[e] += __shfl_xor(acc[e], 32, 64);
            }
            if (lane < 16) {
                float4 o0 = {acc[0], acc[1], acc[2], acc[3]};
                float4 o1 = {acc[4], acc[5], acc[6], acc[7]};
                float4* dst = (float4*)(out_ent + (size_t)h * DD) + l15 * 2;
                dst[0] = o0;
                dst[1] = o1;
            }
        }
    } else {
        const int u = (blockIdx.x - EDGE_BLOCKS) * 4 + (threadIdx.x >> 6);
        const int n = min(cnt[N_ENT + u], CAP_U);
        const int2* seg = pack_u + (size_t)u * CAP_U;
        float ax = 0.f, ay = 0.f;
        for (int j = 0; j < n; j += 8) {
            int2 pk[8];
#pragma unroll
            for (int k = 0; k < 8; ++k) pk[k] = seg[min(j + k, n - 1)];
            unsigned int bv[8];
            float sc[8];
#pragma unroll
            for (int k = 0; k < 8; ++k) {
                sc[k] = (j + k < n) ? __int_as_float(pk[k].y) : 0.f;
                bv[k] = ((const unsigned int*)(entbf + (size_t)pk[k].x * DD))[lane];
            }
#pragma unroll
            for (int k = 0; k < 8; ++k) {
                ax = fmaf(bflo(bv[k]), sc[k], ax);
                ay = fmaf(bfhi(bv[k]), sc[k], ay);
            }
        }
#pragma unroll
        for (int k = 0; k < SPLITK; ++k) {
            float2 p = ((const float2*)(part + (size_t)k * N_USR * DD + (size_t)u * DD))[lane];
            ax += p.x;
            ay += p.y;
        }
        float2 o; o.x = ax; o.y = ay;
        ((float2*)(out_usr + (size_t)u * DD))[lane] = o;
    }
}

// ---------------------------------------------------------------------------
static constexpr size_t algn(size_t x) { return (x + 255) & ~(size_t)255; }

extern "C" void kernel_launch(void* const* d_in, const int* in_sizes, int n_in,
                              void* d_out, int out_size, void* d_ws, size_t ws_size,
                              hipStream_t stream) {
    const float* ent  = (const float*)d_in[0];
    const float* item = (const float*)d_in[1];
    const float* usr  = (const float*)d_in[2];
    const float* rel  = (const float*)d_in[4];
    const int*   eidx = (const int*)d_in[5];
    const int*   etyp = (const int*)d_in[6];
    const float* eimp = (const float*)d_in[7];
    const int*   irow = (const int*)d_in[8];
    const int*   icol = (const int*)d_in[9];
    const float* ival = (const float*)d_in[10];
    const float* uclw = (const float*)d_in[13];
    const float* icm  = (const float*)d_in[14];

    float* out_ent = (float*)d_out;
    float* out_usr = out_ent + (size_t)N_ENT * DD;

    char* w = (char*)d_ws;
    size_t o = 0;
    float* ws_att  = (float*)(w + o);  o = algn(o + (size_t)N_ENT * N_REL * 4);
    float* ws_uatt = (float*)(w + o);  o = algn(o + (size_t)N_USR * N_CLS * 4);
    unsigned short* ws_Bt    = (unsigned short*)(w + o); o = algn(o + (size_t)DD * N_ITEM * 2);
    unsigned short* ws_entbf = (unsigned short*)(w + o); o = algn(o + (size_t)N_ENT * DD * 2);
    unsigned short* ws_relbf = (unsigned short*)(w + o); o = algn(o + (size_t)N_REL * DD * 2);
    unsigned short* ws_Abf   = (unsigned short*)(w + o); o = algn(o + (size_t)N_USR * N_ITEM * 2);
    int*  ws_cnt   = (int*)(w + o);  o = algn(o + (size_t)(N_ENT + N_USR) * 4);
    int2* pack_e   = (int2*)(w + o); o = algn(o + (size_t)N_ENT * CAP_E * 8);
    int2* pack_u   = (int2*)(w + o); o = algn(o + (size_t)N_USR * CAP_U * 8);
    float* part    = (float*)(w + o); o = algn(o + (size_t)SPLITK * N_USR * DD * 4);

    (void)in_sizes; (void)n_in; (void)ws_size; (void)out_size;

    // 4 nodes: prep_light -> {combine(rotated) || ent_att || scatter} -> gemm -> {edge || user}
    k_prep_light<<<ZB + 1024 + 16, 256, 0, stream>>>(rel, ws_cnt, item, ws_Bt,
                                                     usr, uclw, ws_uatt);
    k_node2<<<CB_BLOCKS + EAB + SCAT_BLOCKS, 256, 0, stream>>>(
        icm, ws_uatt, ws_Abf, ent, rel, ws_att, ws_entbf, ws_relbf,
        eidx, etyp, eimp, irow, icol, ival, ws_cnt, pack_e, pack_u);
    k_gemm2<<<dim3(N_USR / BM, SPLITK), 256, 0, stream>>>(ws_Abf, ws_Bt, part);
    k_node3<<<EDGE_BLOCKS + USER_BLOCKS, 256, 0, stream>>>(ws_entbf, ws_relbf, ws_att,
                                                           pack_e, pack_u, ws_cnt, part,
                                                           out_ent, out_usr);
}

// Round 19
// 275.073 us; speedup vs baseline: 1.2201x; 1.0922x over previous
//
#include <hip/hip_runtime.h>

#define N_ENT   100000
#define N_USR   4096
#define N_ITEM  8192
#define N_REL   32
#define N_CLS   3
#define DD      128
#define N_EDGES 800000
#define NNZ     204800

#define CAP_E   64
#define CAP_U   128

typedef __attribute__((ext_vector_type(8))) short short8;
typedef __attribute__((ext_vector_type(4))) float f32x4;

static __device__ __forceinline__ unsigned short f2bf(float x) {
    unsigned int u = __builtin_bit_cast(unsigned int, x);
    u = (u + 0x7fffu + ((u >> 16) & 1u)) >> 16;
    return (unsigned short)u;
}
static __device__ __forceinline__ float bflo(unsigned int v) {
    return __uint_as_float(v << 16);
}
static __device__ __forceinline__ float bfhi(unsigned int v) {
    return __uint_as_float(v & 0xffff0000u);
}

// ---------------- node 1: light prep {zero cnt | item2 -> Bt | uatt} -------
#define ZB  ((N_ENT + N_USR + 255) / 256)   // 407

__global__ __launch_bounds__(256) void k_prep_light(const float* __restrict__ rel,
                                                    int* __restrict__ cnt,
                                                    const float* __restrict__ item,
                                                    unsigned short* __restrict__ Bt,
                                                    const float* __restrict__ usr,
                                                    const float* __restrict__ w,
                                                    float* __restrict__ uatt) {
    __shared__ float smem[32 * 33 + 32];
    int bx = blockIdx.x;

    if (bx < ZB) {
        int i = bx * 256 + threadIdx.x;
        if (i < N_ENT + N_USR) cnt[i] = 0;
        return;
    }
    bx -= ZB;

    if (bx < 1024) {                        // ---- item2 tiled transpose -> Bt ----
        float (*tile)[33] = (float(*)[33])smem;
        float* ssum = smem + 32 * 33;
        const int b2 = bx & 255, by = bx >> 8;
        const int tx = threadIdx.x & 31, ty = threadIdx.x >> 5;
        const int i0 = b2 * 32, d0 = by * 32;
        if (threadIdx.x < 32) {
            float s = 0.f;
            for (int r = 0; r < N_REL; ++r) s += rel[r * DD + d0 + threadIdx.x];
            ssum[threadIdx.x] = s;
        }
#pragma unroll
        for (int rr = 0; rr < 4; ++rr)
            tile[ty + 8 * rr][tx] = item[(size_t)(i0 + ty + 8 * rr) * DD + d0 + tx];
        __syncthreads();
#pragma unroll
        for (int rr = 0; rr < 4; ++rr) {
            int d = d0 + ty + 8 * rr;
            Bt[(size_t)d * N_ITEM + i0 + tx] = f2bf(tile[tx][ty + 8 * rr] * ssum[ty + 8 * rr]);
        }
        return;
    }
    bx -= 1024;

    {                                       // ---- user_cls_att (16 blocks) ----
        for (int i = threadIdx.x; i < N_CLS * DD; i += 256) smem[i] = w[i];
        __syncthreads();
        int u = bx * 256 + threadIdx.x;
        const float4* row = (const float4*)(usr + (size_t)u * DD);
        float acc[3] = {0.f, 0.f, 0.f};
        for (int dq = 0; dq < DD / 4; ++dq) {
            float4 v = row[dq];
#pragma unroll
            for (int c = 0; c < 3; ++c) {
                float4 ww = *(const float4*)&smem[c * DD + dq * 4];
                acc[c] += v.x * ww.x + v.y * ww.y + v.z * ww.z + v.w * ww.w;
            }
        }
        float m = fmaxf(acc[0], fmaxf(acc[1], acc[2]));
        float s = 0.f;
#pragma unroll
        for (int c = 0; c < 3; ++c) { acc[c] = __expf(acc[c] - m); s += acc[c]; }
        float inv = 1.f / s;
#pragma unroll
        for (int c = 0; c < 3; ++c) uatt[u * 3 + c] = acc[c] * inv;
    }
}

// ---------------- node 2: {disen GEMM (BM=32, no-spill) || ent_att || scatter}
// r12 structure (best measured: everything folded under the ~2.3 TB/s icm-read
// wall) with the gemm branch shrunk to fit the 64-VGPR budget the merged
// kernel gets: BM 64->32 halves acc (16 regs) and A-staging (12 regs), so the
// ~135MB of scratch-spill traffic that rode under the wall disappears.
#define BM 32
#define BK 32
#define SPLITK 16
#define KCH (N_ITEM / SPLITK)                 // 512
#define NSTEP (KCH / BK)                      // 16
#define PLANE ((long long)N_USR * N_ITEM)
#define GEMM_BLOCKS ((N_USR / BM) * SPLITK)   // 2048
#define EAB ((N_ENT + 255) / 256)             // 391
#define SCAT_BLOCKS ((N_EDGES + 255) / 256)   // 3125

__global__ __launch_bounds__(256) void k_node2(const float* __restrict__ icm,
                                               const unsigned short* __restrict__ Bt,
                                               const float* __restrict__ uatt,
                                               float* __restrict__ part,
                                               const float* __restrict__ ent,
                                               const float* __restrict__ rel,
                                               float* __restrict__ att,
                                               unsigned short* __restrict__ entbf,
                                               unsigned short* __restrict__ relbf,
                                               const int* __restrict__ eidx,
                                               const int* __restrict__ etyp,
                                               const float* __restrict__ eimp,
                                               const int* __restrict__ irow,
                                               const int* __restrict__ icol,
                                               const float* __restrict__ ival,
                                               int* __restrict__ cnt,
                                               int2* __restrict__ pack_e,
                                               int2* __restrict__ pack_u) {
    __shared__ float smemf[N_REL * DD];       // 16 KB union

    if (blockIdx.x < GEMM_BLOCKS) {
        // ================= GEMM branch (BM=32) =============================
        unsigned short* smem = (unsigned short*)smemf;
        unsigned short (*sA)[40] = (unsigned short(*)[40])smem;              // [32][40]
        unsigned short (*sB)[40] = (unsigned short(*)[40])(smem + BM * 40);  // [128][40]

        const int t  = threadIdx.x;
        const int m0 = (blockIdx.x & 127) * BM;
        const int ky = blockIdx.x >> 7;
        const long long k0b = (long long)ky * KCH;

        const int ua = t >> 3;                // 0..31 (one row per thread)
        const int qa = t & 7;
        const float a0 = uatt[(m0 + ua) * 3 + 0];
        const float a1 = uatt[(m0 + ua) * 3 + 1];
        const float a2 = uatt[(m0 + ua) * 3 + 2];

        const int db = t >> 2;                // 0..63
        const int qb = t & 3;

        const int lane = t & 63;
        const int wv = t >> 6;
        const int wm = wv >> 1, wn = wv & 1;  // 2x2 waves: 16 rows x 64 cols each
        const int la = lane & 15, lb = lane >> 4;

        f32x4 acc[4];
#pragma unroll
        for (int ni = 0; ni < 4; ++ni) {
            f32x4 z = {0.f, 0.f, 0.f, 0.f};
            acc[ni] = z;
        }

        float4 rA[3];
        short8 rB0, rB1;
        {
            const long long b0 = (long long)(m0 + ua) * N_ITEM + k0b + qa * 4;
            rA[0] = *(const float4*)(icm + b0);
            rA[1] = *(const float4*)(icm + b0 + PLANE);
            rA[2] = *(const float4*)(icm + b0 + 2 * PLANE);
            const unsigned short* g0 = Bt + (long long)db * N_ITEM + k0b + qb * 8;
            rB0 = *(const short8*)g0;
            rB1 = *(const short8*)(g0 + 64ll * N_ITEM);
        }

        for (int kk = 0; kk < KCH; kk += BK) {
            __syncthreads();
            {
                ushort4 p;
                p.x = f2bf(a0 * rA[0].x + a1 * rA[1].x + a2 * rA[2].x);
                p.y = f2bf(a0 * rA[0].y + a1 * rA[1].y + a2 * rA[2].y);
                p.z = f2bf(a0 * rA[0].z + a1 * rA[1].z + a2 * rA[2].z);
                p.w = f2bf(a0 * rA[0].w + a1 * rA[1].w + a2 * rA[2].w);
                *(ushort4*)(&sA[ua][0] + qa * 4) = p;
                *(short8*)(&sB[db][0] + qb * 8) = rB0;
                *(short8*)(&sB[db + 64][0] + qb * 8) = rB1;
            }
            __syncthreads();

            if (kk + BK < KCH) {
                const long long k0 = k0b + kk + BK;
                const long long b0 = (long long)(m0 + ua) * N_ITEM + k0 + qa * 4;
                rA[0] = *(const float4*)(icm + b0);
                rA[1] = *(const float4*)(icm + b0 + PLANE);
                rA[2] = *(const float4*)(icm + b0 + 2 * PLANE);
                const unsigned short* g0 = Bt + (long long)db * N_ITEM + k0 + qb * 8;
                rB0 = *(const short8*)g0;
                rB1 = *(const short8*)(g0 + 64ll * N_ITEM);
            }

            short8 af, bfr[4];
            af = *(const short8*)(&sA[wm * 16 + la][0] + lb * 8);
#pragma unroll
            for (int ni = 0; ni < 4; ++ni)
                bfr[ni] = *(const short8*)(&sB[wn * 64 + ni * 16 + la][0] + lb * 8);
#pragma unroll
            for (int ni = 0; ni < 4; ++ni)
                acc[ni] = __builtin_amdgcn_mfma_f32_16x16x32_bf16(af, bfr[ni], acc[ni], 0, 0, 0);
        }

        float* pbase = part + (size_t)ky * ((size_t)N_USR * DD);
#pragma unroll
        for (int ni = 0; ni < 4; ++ni)
#pragma unroll
            for (int r = 0; r < 4; ++r) {
                int row = m0 + wm * 16 + lb * 4 + r;
                int col = wn * 64 + ni * 16 + la;
                pbase[(size_t)row * DD + col] = acc[ni][r];
            }
        return;
    }

    if (blockIdx.x < GEMM_BLOCKS + EAB) {
        // ================= ent_att + bf16 tables ===========================
        int bx = blockIdx.x - GEMM_BLOCKS;
        for (int i = threadIdx.x; i < N_REL * DD; i += 256) smemf[i] = rel[i];
        __syncthreads();
        if (bx == 0) {
            for (int i = threadIdx.x; i < N_REL * DD; i += 256)
                relbf[i] = f2bf(smemf[i]);
        }
        int e = bx * 256 + threadIdx.x;
        if (e >= N_ENT) return;
        const float4* row = (const float4*)(ent + (size_t)e * DD);
        unsigned short* brow = entbf + (size_t)e * DD;
        float acc[N_REL];
#pragma unroll
        for (int r = 0; r < N_REL; ++r) acc[r] = 0.f;
        for (int dq = 0; dq < DD / 4; ++dq) {
            float4 v = row[dq];
            ushort4 bv;
            bv.x = f2bf(v.x); bv.y = f2bf(v.y); bv.z = f2bf(v.z); bv.w = f2bf(v.w);
            *(ushort4*)(brow + dq * 4) = bv;
#pragma unroll
            for (int r = 0; r < N_REL; ++r) {
                float4 ww = *(const float4*)&smemf[r * DD + dq * 4];
                acc[r] += v.x * ww.x + v.y * ww.y + v.z * ww.z + v.w * ww.w;
            }
        }
        float m = acc[0];
#pragma unroll
        for (int r = 1; r < N_REL; ++r) m = fmaxf(m, acc[r]);
        float s = 0.f;
#pragma unroll
        for (int r = 0; r < N_REL; ++r) { acc[r] = __expf(acc[r] - m); s += acc[r]; }
        float inv = 1.f / s;
        float* o = att + (size_t)e * N_REL;
#pragma unroll
        for (int r = 0; r < N_REL; ++r) o[r] = acc[r] * inv;
        return;
    }

    {
        // ================= bucket scatter ==================================
        int i = (blockIdx.x - GEMM_BLOCKS - EAB) * 256 + threadIdx.x;
        if (i < N_EDGES) {
            int h = eidx[i], tl = eidx[N_EDGES + i], r = etyp[i];
            int p = atomicAdd(&cnt[h], 1);
            if (p < CAP_E) {
                int2 pk;
                pk.x = tl | (r << 24);
                pk.y = __float_as_int(eimp[i]);
                pack_e[(size_t)h * CAP_E + p] = pk;
            }
        }
        if (i < NNZ) {
            int u = irow[i];
            int p = atomicAdd(&cnt[N_ENT + u], 1);
            if (p < CAP_U) {
                int2 pk;
                pk.x = icol[i];
                pk.y = __float_as_int(ival[i]);
                pack_u[(size_t)u * CAP_U + p] = pk;
            }
        }
    }
}

// ---------------- node 3: {edge agg (16-lane groups) || user gather} -------
#define EDGE_BLOCKS (N_ENT / 16)     // 6250
#define USER_BLOCKS (N_USR / 4)      // 1024

__global__ __launch_bounds__(256) void k_node3(const unsigned short* __restrict__ entbf,
                                               const unsigned short* __restrict__ relbf,
                                               const float* __restrict__ att,
                                               const int2* __restrict__ pack_e,
                                               const int2* __restrict__ pack_u,
                                               const int* __restrict__ cnt,
                                               const float* __restrict__ part,
                                               float* __restrict__ out_ent,
                                               float* __restrict__ out_usr) {
    const int lane = threadIdx.x & 63;

    if (blockIdx.x < EDGE_BLOCKS) {
        const int wid = blockIdx.x * 4 + (threadIdx.x >> 6);
        const int l15 = lane & 15;
        const int grp = lane >> 4;
#pragma unroll 1
        for (int hh = 0; hh < 4; ++hh) {
            const int h = wid * 4 + hh;
            const int n = min(cnt[h], CAP_E);
            const float attv = att[(size_t)h * N_REL + (lane & 31)];
            const int2* seg = pack_e + (size_t)h * CAP_E;
            float acc[8];
#pragma unroll
            for (int e = 0; e < 8; ++e) acc[e] = 0.f;
            for (int j = 0; j < n; j += 8) {
                const int e0 = j + grp, e1 = j + 4 + grp;
                int2 p0 = seg[min(e0, n - 1)];
                int2 p1 = seg[min(e1, n - 1)];
                const int r0 = ((unsigned)p0.x) >> 24;
                const int r1 = ((unsigned)p1.x) >> 24;
                float s0 = __shfl(attv, r0, 64) * __int_as_float(p0.y);
                float s1 = __shfl(attv, r1, 64) * __int_as_float(p1.y);
                s0 = (e0 < n) ? s0 : 0.f;
                s1 = (e1 < n) ? s1 : 0.f;
                uint4 b0 = ((const uint4*)(entbf + (size_t)(p0.x & 0xFFFFFF) * DD))[l15];
                uint4 b1 = ((const uint4*)(entbf + (size_t)(p1.x & 0xFFFFFF) * DD))[l15];
                uint4 v0 = ((const uint4*)(relbf + (size_t)r0 * DD))[l15];
                uint4 v1 = ((const uint4*)(relbf + (size_t)r1 * DD))[l15];
                const unsigned* bp0 = (const unsigned*)&b0;
                const unsigned* bp1 = (const unsigned*)&b1;
                const unsigned* vp0 = (const unsigned*)&v0;
                const unsigned* vp1 = (const unsigned*)&v1;
#pragma unroll
                for (int q = 0; q < 4; ++q) {
                    acc[2 * q]     = fmaf(bflo(bp0[q]) * bflo(vp0[q]), s0, acc[2 * q]);
                    acc[2 * q + 1] = fmaf(bfhi(bp0[q]) * bfhi(vp0[q]), s0, acc[2 * q + 1]);
                    acc[2 * q]     = fmaf(bflo(bp1[q]) * bflo(vp1[q]), s1, acc[2 * q]);
                    acc[2 * q + 1] = fmaf(bfhi(bp1[q]) * bfhi(vp1[q]), s1, acc[2 * q + 1]);
                }
            }
#pragma unroll
            for (int e = 0; e < 8; ++e) {
                acc[e] += __shfl_xor(acc[e], 16, 64);
                acc[e] += __shfl_xor(acc[e], 32, 64);
            }
            if (lane < 16) {
                float4 o0 = {acc[0], acc[1], acc[2], acc[3]};
                float4 o1 = {acc[4], acc[5], acc[6], acc[7]};
                float4* dst = (float4*)(out_ent + (size_t)h * DD) + l15 * 2;
                dst[0] = o0;
                dst[1] = o1;
            }
        }
    } else {
        const int u = (blockIdx.x - EDGE_BLOCKS) * 4 + (threadIdx.x >> 6);
        const int n = min(cnt[N_ENT + u], CAP_U);
        const int2* seg = pack_u + (size_t)u * CAP_U;
        float ax = 0.f, ay = 0.f;
        for (int j = 0; j < n; j += 8) {
            int2 pk[8];
#pragma unroll
            for (int k = 0; k < 8; ++k) pk[k] = seg[min(j + k, n - 1)];
            unsigned int bv[8];
            float sc[8];
#pragma unroll
            for (int k = 0; k < 8; ++k) {
                sc[k] = (j + k < n) ? __int_as_float(pk[k].y) : 0.f;
                bv[k] = ((const unsigned int*)(entbf + (size_t)pk[k].x * DD))[lane];
            }
#pragma unroll
            for (int k = 0; k < 8; ++k) {
                ax = fmaf(bflo(bv[k]), sc[k], ax);
                ay = fmaf(bfhi(bv[k]), sc[k], ay);
            }
        }
#pragma unroll
        for (int k = 0; k < SPLITK; ++k) {
            float2 p = ((const float2*)(part + (size_t)k * N_USR * DD + (size_t)u * DD))[lane];
            ax += p.x;
            ay += p.y;
        }
        float2 o; o.x = ax; o.y = ay;
        ((float2*)(out_usr + (size_t)u * DD))[lane] = o;
    }
}

// ---------------------------------------------------------------------------
static constexpr size_t algn(size_t x) { return (x + 255) & ~(size_t)255; }

extern "C" void kernel_launch(void* const* d_in, const int* in_sizes, int n_in,
                              void* d_out, int out_size, void* d_ws, size_t ws_size,
                              hipStream_t stream) {
    const float* ent  = (const float*)d_in[0];
    const float* item = (const float*)d_in[1];
    const float* usr  = (const float*)d_in[2];
    const float* rel  = (const float*)d_in[4];
    const int*   eidx = (const int*)d_in[5];
    const int*   etyp = (const int*)d_in[6];
    const float* eimp = (const float*)d_in[7];
    const int*   irow = (const int*)d_in[8];
    const int*   icol = (const int*)d_in[9];
    const float* ival = (const float*)d_in[10];
    const float* uclw = (const float*)d_in[13];
    const float* icm  = (const float*)d_in[14];

    float* out_ent = (float*)d_out;
    float* out_usr = out_ent + (size_t)N_ENT * DD;

    char* w = (char*)d_ws;
    size_t o = 0;
    float* ws_att  = (float*)(w + o);  o = algn(o + (size_t)N_ENT * N_REL * 4);
    float* ws_uatt = (float*)(w + o);  o = algn(o + (size_t)N_USR * N_CLS * 4);
    unsigned short* ws_Bt    = (unsigned short*)(w + o); o = algn(o + (size_t)DD * N_ITEM * 2);
    unsigned short* ws_entbf = (unsigned short*)(w + o); o = algn(o + (size_t)N_ENT * DD * 2);
    unsigned short* ws_relbf = (unsigned short*)(w + o); o = algn(o + (size_t)N_REL * DD * 2);
    int*  ws_cnt   = (int*)(w + o);  o = algn(o + (size_t)(N_ENT + N_USR) * 4);
    int2* pack_e   = (int2*)(w + o); o = algn(o + (size_t)N_ENT * CAP_E * 8);
    int2* pack_u   = (int2*)(w + o); o = algn(o + (size_t)N_USR * CAP_U * 8);
    float* part    = (float*)(w + o); o = algn(o + (size_t)SPLITK * N_USR * DD * 4);

    (void)in_sizes; (void)n_in; (void)ws_size; (void)out_size;

    // 3 nodes (r12 structure, no-spill gemm):
    // prep_light -> {gemm(BM32) || ent_att || scatter} -> {edge || user}
    k_prep_light<<<ZB + 1024 + 16, 256, 0, stream>>>(rel, ws_cnt, item, ws_Bt,
                                                     usr, uclw, ws_uatt);
    k_node2<<<GEMM_BLOCKS + EAB + SCAT_BLOCKS, 256, 0, stream>>>(
        icm, ws_Bt, ws_uatt, part, ent, rel, ws_att, ws_entbf, ws_relbf,
        eidx, etyp, eimp, irow, icol, ival, ws_cnt, pack_e, pack_u);
    k_node3<<<EDGE_BLOCKS + USER_BLOCKS, 256, 0, stream>>>(ws_entbf, ws_relbf, ws_att,
                                                           pack_e, pack_u, ws_cnt, part,
                                                           out_ent, out_usr);
}

// Round 20
// 268.216 us; speedup vs baseline: 1.2513x; 1.0256x over previous
//
#include <hip/hip_runtime.h>

#define N_ENT   100000
#define N_USR   4096
#define N_ITEM  8192
#define N_REL   32
#define N_CLS   3
#define DD      128
#define N_EDGES 800000
#define NNZ     204800

#define CAP_E   64
#define CAP_U   128

typedef __attribute__((ext_vector_type(8))) short short8;
typedef __attribute__((ext_vector_type(4))) float f32x4;

static __device__ __forceinline__ unsigned short f2bf(float x) {
    unsigned int u = __builtin_bit_cast(unsigned int, x);
    u = (u + 0x7fffu + ((u >> 16) & 1u)) >> 16;
    return (unsigned short)u;
}
static __device__ __forceinline__ float bflo(unsigned int v) {
    return __uint_as_float(v << 16);
}
static __device__ __forceinline__ float bfhi(unsigned int v) {
    return __uint_as_float(v & 0xffff0000u);
}
// non-temporal helpers: bypass cache-RFO on scattered stores, avoid L2/L3
// pollution on zero-reuse streams (gfx950 buffer 'nt' flag).
static __device__ __forceinline__ f32x4 ntld4(const float* p) {
    return __builtin_nontemporal_load((const f32x4*)p);
}
static __device__ __forceinline__ void ntst8(void* p, int2 v) {
    __builtin_nontemporal_store(__builtin_bit_cast(long long, v), (long long*)p);
}
static __device__ __forceinline__ void ntstf(float* p, float v) {
    __builtin_nontemporal_store(v, p);
}

// ---------------- node 1: light prep {zero cnt | item2 -> Bt | uatt} -------
#define ZB  ((N_ENT + N_USR + 255) / 256)   // 407

__global__ __launch_bounds__(256) void k_prep_light(const float* __restrict__ rel,
                                                    int* __restrict__ cnt,
                                                    const float* __restrict__ item,
                                                    unsigned short* __restrict__ Bt,
                                                    const float* __restrict__ usr,
                                                    const float* __restrict__ w,
                                                    float* __restrict__ uatt) {
    __shared__ float smem[32 * 33 + 32];
    int bx = blockIdx.x;

    if (bx < ZB) {
        int i = bx * 256 + threadIdx.x;
        if (i < N_ENT + N_USR) cnt[i] = 0;
        return;
    }
    bx -= ZB;

    if (bx < 1024) {                        // ---- item2 tiled transpose -> Bt ----
        float (*tile)[33] = (float(*)[33])smem;
        float* ssum = smem + 32 * 33;
        const int b2 = bx & 255, by = bx >> 8;
        const int tx = threadIdx.x & 31, ty = threadIdx.x >> 5;
        const int i0 = b2 * 32, d0 = by * 32;
        if (threadIdx.x < 32) {
            float s = 0.f;
            for (int r = 0; r < N_REL; ++r) s += rel[r * DD + d0 + threadIdx.x];
            ssum[threadIdx.x] = s;
        }
#pragma unroll
        for (int rr = 0; rr < 4; ++rr)
            tile[ty + 8 * rr][tx] = item[(size_t)(i0 + ty + 8 * rr) * DD + d0 + tx];
        __syncthreads();
#pragma unroll
        for (int rr = 0; rr < 4; ++rr) {
            int d = d0 + ty + 8 * rr;
            Bt[(size_t)d * N_ITEM + i0 + tx] = f2bf(tile[tx][ty + 8 * rr] * ssum[ty + 8 * rr]);
        }
        return;
    }
    bx -= 1024;

    {                                       // ---- user_cls_att (16 blocks) ----
        for (int i = threadIdx.x; i < N_CLS * DD; i += 256) smem[i] = w[i];
        __syncthreads();
        int u = bx * 256 + threadIdx.x;
        const float4* row = (const float4*)(usr + (size_t)u * DD);
        float acc[3] = {0.f, 0.f, 0.f};
        for (int dq = 0; dq < DD / 4; ++dq) {
            float4 v = row[dq];
#pragma unroll
            for (int c = 0; c < 3; ++c) {
                float4 ww = *(const float4*)&smem[c * DD + dq * 4];
                acc[c] += v.x * ww.x + v.y * ww.y + v.z * ww.z + v.w * ww.w;
            }
        }
        float m = fmaxf(acc[0], fmaxf(acc[1], acc[2]));
        float s = 0.f;
#pragma unroll
        for (int c = 0; c < 3; ++c) { acc[c] = __expf(acc[c] - m); s += acc[c]; }
        float inv = 1.f / s;
#pragma unroll
        for (int c = 0; c < 3; ++c) uatt[u * 3 + c] = acc[c] * inv;
    }
}

// ---------------- node 2: {disen GEMM (BM=32,NT) || ent_att || scatter(NT)} -
// r19 finding: node2 time == total traffic / ~2.2 TB/s; WRITE_SIZE 208MB vs
// ~78 legit => ~130MB is RFO/partial-line amplification from the 1M random
// 8B pack stores. NT stores (no RFO) + NT icm loads (no L3 thrash) cut it.
#define BM 32
#define BK 32
#define SPLITK 16
#define KCH (N_ITEM / SPLITK)                 // 512
#define PLANE ((long long)N_USR * N_ITEM)
#define GEMM_BLOCKS ((N_USR / BM) * SPLITK)   // 2048
#define EAB ((N_ENT + 255) / 256)             // 391
#define SCAT_BLOCKS ((N_EDGES + 255) / 256)   // 3125

__global__ __launch_bounds__(256) void k_node2(const float* __restrict__ icm,
                                               const unsigned short* __restrict__ Bt,
                                               const float* __restrict__ uatt,
                                               float* __restrict__ part,
                                               const float* __restrict__ ent,
                                               const float* __restrict__ rel,
                                               float* __restrict__ att,
                                               unsigned short* __restrict__ entbf,
                                               unsigned short* __restrict__ relbf,
                                               const int* __restrict__ eidx,
                                               const int* __restrict__ etyp,
                                               const float* __restrict__ eimp,
                                               const int* __restrict__ irow,
                                               const int* __restrict__ icol,
                                               const float* __restrict__ ival,
                                               int* __restrict__ cnt,
                                               int2* __restrict__ pack_e,
                                               int2* __restrict__ pack_u) {
    __shared__ float smemf[N_REL * DD];       // 16 KB union

    if (blockIdx.x < GEMM_BLOCKS) {
        // ================= GEMM branch (BM=32, NT icm loads) ===============
        unsigned short* smem = (unsigned short*)smemf;
        unsigned short (*sA)[40] = (unsigned short(*)[40])smem;
        unsigned short (*sB)[40] = (unsigned short(*)[40])(smem + BM * 40);

        const int t  = threadIdx.x;
        const int m0 = (blockIdx.x & 127) * BM;
        const int ky = blockIdx.x >> 7;
        const long long k0b = (long long)ky * KCH;

        const int ua = t >> 3;
        const int qa = t & 7;
        const float a0 = uatt[(m0 + ua) * 3 + 0];
        const float a1 = uatt[(m0 + ua) * 3 + 1];
        const float a2 = uatt[(m0 + ua) * 3 + 2];

        const int db = t >> 2;
        const int qb = t & 3;

        const int lane = t & 63;
        const int wv = t >> 6;
        const int wm = wv >> 1, wn = wv & 1;
        const int la = lane & 15, lb = lane >> 4;

        f32x4 acc[4];
#pragma unroll
        for (int ni = 0; ni < 4; ++ni) {
            f32x4 z = {0.f, 0.f, 0.f, 0.f};
            acc[ni] = z;
        }

        f32x4 rA[3];
        short8 rB0, rB1;
        {
            const long long b0 = (long long)(m0 + ua) * N_ITEM + k0b + qa * 4;
            rA[0] = ntld4(icm + b0);
            rA[1] = ntld4(icm + b0 + PLANE);
            rA[2] = ntld4(icm + b0 + 2 * PLANE);
            const unsigned short* g0 = Bt + (long long)db * N_ITEM + k0b + qb * 8;
            rB0 = *(const short8*)g0;
            rB1 = *(const short8*)(g0 + 64ll * N_ITEM);
        }

        for (int kk = 0; kk < KCH; kk += BK) {
            __syncthreads();
            {
                ushort4 p;
                p.x = f2bf(a0 * rA[0][0] + a1 * rA[1][0] + a2 * rA[2][0]);
                p.y = f2bf(a0 * rA[0][1] + a1 * rA[1][1] + a2 * rA[2][1]);
                p.z = f2bf(a0 * rA[0][2] + a1 * rA[1][2] + a2 * rA[2][2]);
                p.w = f2bf(a0 * rA[0][3] + a1 * rA[1][3] + a2 * rA[2][3]);
                *(ushort4*)(&sA[ua][0] + qa * 4) = p;
                *(short8*)(&sB[db][0] + qb * 8) = rB0;
                *(short8*)(&sB[db + 64][0] + qb * 8) = rB1;
            }
            __syncthreads();

            if (kk + BK < KCH) {
                const long long k0 = k0b + kk + BK;
                const long long b0 = (long long)(m0 + ua) * N_ITEM + k0 + qa * 4;
                rA[0] = ntld4(icm + b0);
                rA[1] = ntld4(icm + b0 + PLANE);
                rA[2] = ntld4(icm + b0 + 2 * PLANE);
                const unsigned short* g0 = Bt + (long long)db * N_ITEM + k0 + qb * 8;
                rB0 = *(const short8*)g0;
                rB1 = *(const short8*)(g0 + 64ll * N_ITEM);
            }

            short8 af, bfr[4];
            af = *(const short8*)(&sA[wm * 16 + la][0] + lb * 8);
#pragma unroll
            for (int ni = 0; ni < 4; ++ni)
                bfr[ni] = *(const short8*)(&sB[wn * 64 + ni * 16 + la][0] + lb * 8);
#pragma unroll
            for (int ni = 0; ni < 4; ++ni)
                acc[ni] = __builtin_amdgcn_mfma_f32_16x16x32_bf16(af, bfr[ni], acc[ni], 0, 0, 0);
        }

        float* pbase = part + (size_t)ky * ((size_t)N_USR * DD);
#pragma unroll
        for (int ni = 0; ni < 4; ++ni)
#pragma unroll
            for (int r = 0; r < 4; ++r) {
                int row = m0 + wm * 16 + lb * 4 + r;
                int col = wn * 64 + ni * 16 + la;
                ntstf(pbase + (size_t)row * DD + col, acc[ni][r]);
            }
        return;
    }

    if (blockIdx.x < GEMM_BLOCKS + EAB) {
        // ================= ent_att + bf16 tables ===========================
        int bx = blockIdx.x - GEMM_BLOCKS;
        for (int i = threadIdx.x; i < N_REL * DD; i += 256) smemf[i] = rel[i];
        __syncthreads();
        if (bx == 0) {
            for (int i = threadIdx.x; i < N_REL * DD; i += 256)
                relbf[i] = f2bf(smemf[i]);
        }
        int e = bx * 256 + threadIdx.x;
        if (e >= N_ENT) return;
        const float4* row = (const float4*)(ent + (size_t)e * DD);
        unsigned short* brow = entbf + (size_t)e * DD;
        float acc[N_REL];
#pragma unroll
        for (int r = 0; r < N_REL; ++r) acc[r] = 0.f;
        for (int dq = 0; dq < DD / 4; ++dq) {
            float4 v = row[dq];
            ushort4 bv;
            bv.x = f2bf(v.x); bv.y = f2bf(v.y); bv.z = f2bf(v.z); bv.w = f2bf(v.w);
            *(ushort4*)(brow + dq * 4) = bv;
#pragma unroll
            for (int r = 0; r < N_REL; ++r) {
                float4 ww = *(const float4*)&smemf[r * DD + dq * 4];
                acc[r] += v.x * ww.x + v.y * ww.y + v.z * ww.z + v.w * ww.w;
            }
        }
        float m = acc[0];
#pragma unroll
        for (int r = 1; r < N_REL; ++r) m = fmaxf(m, acc[r]);
        float s = 0.f;
#pragma unroll
        for (int r = 0; r < N_REL; ++r) { acc[r] = __expf(acc[r] - m); s += acc[r]; }
        float inv = 1.f / s;
        float* o = att + (size_t)e * N_REL;
#pragma unroll
        for (int r = 0; r < N_REL; ++r) o[r] = acc[r] * inv;
        return;
    }

    {
        // ================= bucket scatter (NT stores, no RFO) ==============
        int i = (blockIdx.x - GEMM_BLOCKS - EAB) * 256 + threadIdx.x;
        if (i < N_EDGES) {
            int h = eidx[i], tl = eidx[N_EDGES + i], r = etyp[i];
            int p = atomicAdd(&cnt[h], 1);
            if (p < CAP_E) {
                int2 pk;
                pk.x = tl | (r << 24);
                pk.y = __float_as_int(eimp[i]);
                ntst8(&pack_e[(size_t)h * CAP_E + p], pk);
            }
        }
        if (i < NNZ) {
            int u = irow[i];
            int p = atomicAdd(&cnt[N_ENT + u], 1);
            if (p < CAP_U) {
                int2 pk;
                pk.x = icol[i];
                pk.y = __float_as_int(ival[i]);
                ntst8(&pack_u[(size_t)u * CAP_U + p], pk);
            }
        }
    }
}

// ---------------- node 3: {edge agg (16-lane groups) || user gather} -------
#define EDGE_BLOCKS (N_ENT / 16)     // 6250
#define USER_BLOCKS (N_USR / 4)      // 1024

__global__ __launch_bounds__(256) void k_node3(const unsigned short* __restrict__ entbf,
                                               const unsigned short* __restrict__ relbf,
                                               const float* __restrict__ att,
                                               const int2* __restrict__ pack_e,
                                               const int2* __restrict__ pack_u,
                                               const int* __restrict__ cnt,
                                               const float* __restrict__ part,
                                               float* __restrict__ out_ent,
                                               float* __restrict__ out_usr) {
    const int lane = threadIdx.x & 63;

    if (blockIdx.x < EDGE_BLOCKS) {
        const int wid = blockIdx.x * 4 + (threadIdx.x >> 6);
        const int l15 = lane & 15;
        const int grp = lane >> 4;
#pragma unroll 1
        for (int hh = 0; hh < 4; ++hh) {
            const int h = wid * 4 + hh;
            const int n = min(cnt[h], CAP_E);
            const float attv = att[(size_t)h * N_REL + (lane & 31)];
            const int2* seg = pack_e + (size_t)h * CAP_E;
            float acc[8];
#pragma unroll
            for (int e = 0; e < 8; ++e) acc[e] = 0.f;
            for (int j = 0; j < n; j += 8) {
                const int e0 = j + grp, e1 = j + 4 + grp;
                int2 p0 = seg[min(e0, n - 1)];
                int2 p1 = seg[min(e1, n - 1)];
                const int r0 = ((unsigned)p0.x) >> 24;
                const int r1 = ((unsigned)p1.x) >> 24;
                float s0 = __shfl(attv, r0, 64) * __int_as_float(p0.y);
                float s1 = __shfl(attv, r1, 64) * __int_as_float(p1.y);
                s0 = (e0 < n) ? s0 : 0.f;
                s1 = (e1 < n) ? s1 : 0.f;
                uint4 b0 = ((const uint4*)(entbf + (size_t)(p0.x & 0xFFFFFF) * DD))[l15];
                uint4 b1 = ((const uint4*)(entbf + (size_t)(p1.x & 0xFFFFFF) * DD))[l15];
                uint4 v0 = ((const uint4*)(relbf + (size_t)r0 * DD))[l15];
                uint4 v1 = ((const uint4*)(relbf + (size_t)r1 * DD))[l15];
                const unsigned* bp0 = (const unsigned*)&b0;
                const unsigned* bp1 = (const unsigned*)&b1;
                const unsigned* vp0 = (const unsigned*)&v0;
                const unsigned* vp1 = (const unsigned*)&v1;
#pragma unroll
                for (int q = 0; q < 4; ++q) {
                    acc[2 * q]     = fmaf(bflo(bp0[q]) * bflo(vp0[q]), s0, acc[2 * q]);
                    acc[2 * q + 1] = fmaf(bfhi(bp0[q]) * bfhi(vp0[q]), s0, acc[2 * q + 1]);
                    acc[2 * q]     = fmaf(bflo(bp1[q]) * bflo(vp1[q]), s1, acc[2 * q]);
                    acc[2 * q + 1] = fmaf(bfhi(bp1[q]) * bfhi(vp1[q]), s1, acc[2 * q + 1]);
                }
            }
#pragma unroll
            for (int e = 0; e < 8; ++e) {
                acc[e] += __shfl_xor(acc[e], 16, 64);
                acc[e] += __shfl_xor(acc[e], 32, 64);
            }
            if (lane < 16) {
                float4 o0 = {acc[0], acc[1], acc[2], acc[3]};
                float4 o1 = {acc[4], acc[5], acc[6], acc[7]};
                float4* dst = (float4*)(out_ent + (size_t)h * DD) + l15 * 2;
                dst[0] = o0;
                dst[1] = o1;
            }
        }
    } else {
        const int u = (blockIdx.x - EDGE_BLOCKS) * 4 + (threadIdx.x >> 6);
        const int n = min(cnt[N_ENT + u], CAP_U);
        const int2* seg = pack_u + (size_t)u * CAP_U;
        float ax = 0.f, ay = 0.f;
        for (int j = 0; j < n; j += 8) {
            int2 pk[8];
#pragma unroll
            for (int k = 0; k < 8; ++k) pk[k] = seg[min(j + k, n - 1)];
            unsigned int bv[8];
            float sc[8];
#pragma unroll
            for (int k = 0; k < 8; ++k) {
                sc[k] = (j + k < n) ? __int_as_float(pk[k].y) : 0.f;
                bv[k] = ((const unsigned int*)(entbf + (size_t)pk[k].x * DD))[lane];
            }
#pragma unroll
            for (int k = 0; k < 8; ++k) {
                ax = fmaf(bflo(bv[k]), sc[k], ax);
                ay = fmaf(bfhi(bv[k]), sc[k], ay);
            }
        }
#pragma unroll
        for (int k = 0; k < SPLITK; ++k) {
            float2 p = ((const float2*)(part + (size_t)k * N_USR * DD + (size_t)u * DD))[lane];
            ax += p.x;
            ay += p.y;
        }
        float2 o; o.x = ax; o.y = ay;
        ((float2*)(out_usr + (size_t)u * DD))[lane] = o;
    }
}

// ---------------------------------------------------------------------------
static constexpr size_t algn(size_t x) { return (x + 255) & ~(size_t)255; }

extern "C" void kernel_launch(void* const* d_in, const int* in_sizes, int n_in,
                              void* d_out, int out_size, void* d_ws, size_t ws_size,
                              hipStream_t stream) {
    const float* ent  = (const float*)d_in[0];
    const float* item = (const float*)d_in[1];
    const float* usr  = (const float*)d_in[2];
    const float* rel  = (const float*)d_in[4];
    const int*   eidx = (const int*)d_in[5];
    const int*   etyp = (const int*)d_in[6];
    const float* eimp = (const float*)d_in[7];
    const int*   irow = (const int*)d_in[8];
    const int*   icol = (const int*)d_in[9];
    const float* ival = (const float*)d_in[10];
    const float* uclw = (const float*)d_in[13];
    const float* icm  = (const float*)d_in[14];

    float* out_ent = (float*)d_out;
    float* out_usr = out_ent + (size_t)N_ENT * DD;

    char* w = (char*)d_ws;
    size_t o = 0;
    float* ws_att  = (float*)(w + o);  o = algn(o + (size_t)N_ENT * N_REL * 4);
    float* ws_uatt = (float*)(w + o);  o = algn(o + (size_t)N_USR * N_CLS * 4);
    unsigned short* ws_Bt    = (unsigned short*)(w + o); o = algn(o + (size_t)DD * N_ITEM * 2);
    unsigned short* ws_entbf = (unsigned short*)(w + o); o = algn(o + (size_t)N_ENT * DD * 2);
    unsigned short* ws_relbf = (unsigned short*)(w + o); o = algn(o + (size_t)N_REL * DD * 2);
    int*  ws_cnt   = (int*)(w + o);  o = algn(o + (size_t)(N_ENT + N_USR) * 4);
    int2* pack_e   = (int2*)(w + o); o = algn(o + (size_t)N_ENT * CAP_E * 8);
    int2* pack_u   = (int2*)(w + o); o = algn(o + (size_t)N_USR * CAP_U * 8);
    float* part    = (float*)(w + o); o = algn(o + (size_t)SPLITK * N_USR * DD * 4);

    (void)in_sizes; (void)n_in; (void)ws_size; (void)out_size;

    // 3 nodes (r19 structure + NT memory ops):
    // prep_light -> {gemm(BM32,NT) || ent_att || scatter(NT)} -> {edge || user}
    k_prep_light<<<ZB + 1024 + 16, 256, 0, stream>>>(rel, ws_cnt, item, ws_Bt,
                                                     usr, uclw, ws_uatt);
    k_node2<<<GEMM_BLOCKS + EAB + SCAT_BLOCKS, 256, 0, stream>>>(
        icm, ws_Bt, ws_uatt, part, ent, rel, ws_att, ws_entbf, ws_relbf,
        eidx, etyp, eimp, irow, icol, ival, ws_cnt, pack_e, pack_u);
    k_node3<<<EDGE_BLOCKS + USER_BLOCKS, 256, 0, stream>>>(ws_entbf, ws_relbf, ws_att,
                                                           pack_e, pack_u, ws_cnt, part,
                                                           out_ent, out_usr);
}